// Round 20
// baseline (123.985 us; speedup 1.0000x reference)
//
#include <hip/hip_runtime.h>
#include <hip/hip_bf16.h>

typedef __attribute__((ext_vector_type(8))) short short8;
typedef __attribute__((ext_vector_type(4))) short short4v;
typedef __attribute__((ext_vector_type(4))) float f32x4;

#define B_ 8
#define T_ 1024
#define D_ 1024
#define H_ 16
#define G_ 4
#define HD_ 64
#define QKVW 1536   // 1024 q | 256 k | 256 v

#define GLOAD16(gp, lp) __builtin_amdgcn_global_load_lds( \
    (const __attribute__((address_space(1))) void*)(gp),  \
    (__attribute__((address_space(3))) void*)(lp), 16, 0, 0)

__device__ __forceinline__ float exp2_fast(float x) {
    return __builtin_amdgcn_exp2f(x);
}

__device__ __forceinline__ short8 pack_bf16x8(float4 a, float4 b) {
    union { short8 s; __hip_bfloat16 h[8]; } u;
    u.h[0] = __float2bfloat16(a.x); u.h[1] = __float2bfloat16(a.y);
    u.h[2] = __float2bfloat16(a.z); u.h[3] = __float2bfloat16(a.w);
    u.h[4] = __float2bfloat16(b.x); u.h[5] = __float2bfloat16(b.y);
    u.h[6] = __float2bfloat16(b.z); u.h[7] = __float2bfloat16(b.w);
    return u.s;
}

// ---------------------------------------------------------------------------
// Both weights: fp32 [K][N] -> bf16 transposed [N][K], one launch (z selects).
// ---------------------------------------------------------------------------
__global__ __launch_bounds__(256) void cvt_transpose2(
    const float* __restrict__ w_qkv, const float* __restrict__ w_o,
    __hip_bfloat16* __restrict__ wqkvT, __hip_bfloat16* __restrict__ woT)
{
    const int z = blockIdx.z;
    const int N = z ? D_ : QKVW;
    const int n0 = blockIdx.x * 32;
    if (n0 >= N) return;
    const float* in = z ? w_o : w_qkv;
    __hip_bfloat16* outT = z ? woT : wqkvT;

    __shared__ float tile[32][33];
    const int k0 = blockIdx.y * 32;
    const int r = threadIdx.x >> 5, c = threadIdx.x & 31;
    #pragma unroll
    for (int i = 0; i < 4; ++i)
        tile[r + i * 8][c] = in[(size_t)(k0 + r + i * 8) * N + n0 + c];
    __syncthreads();
    #pragma unroll
    for (int i = 0; i < 4; ++i)
        outT[(size_t)(n0 + r + i * 8) * D_ + k0 + c] = __float2bfloat16(tile[c][r + i * 8]);
}

// ---------------------------------------------------------------------------
// Fused QKV GEMM (verified best config): fp32 A (cvt fused, reg-staged w/
// swizzled ds_write), B via global_load_lds w/ slot-permuted source.
// 2-buffer 2-phase, 32 KB LDS. Epilogue: q/k L2-norm (+scale-fold on q);
// v written transposed to vt.
// ---------------------------------------------------------------------------
__global__ __launch_bounds__(256) void gemm_qkv(
    const float* __restrict__ Af,
    const __hip_bfloat16* __restrict__ Bt,
    __hip_bfloat16* __restrict__ qkv,
    __hip_bfloat16* __restrict__ vt)
{
    const int M = B_ * T_, K = D_;
    __shared__ __hip_bfloat16 As[2][128 * 32];
    __shared__ __hip_bfloat16 Bs[2][128 * 32];

    const int tid  = threadIdx.x;
    const int lane = tid & 63;
    const int wr   = (tid >> 6) >> 1;
    const int wc   = (tid >> 6) & 1;

    const int rpx = (M >> 7) >> 3;          // 8
    const int xcd = blockIdx.x & 7;
    const int lin = blockIdx.x >> 3;
    const int by  = xcd * rpx + (lin % rpx);
    const int bx  = lin / rpx;
    const int m0 = by * 128;
    const int n0 = bx * 128;

    f32x4 acc[4][4] = {};

    const int sr0 = tid >> 2;               // rows 0..63
    const int sr1 = 64 + sr0;               // rows 64..127
    const int slot  = (tid & 3) ^ ((tid >> 3) & 3);   // swizzled 16B slot
    const int sc_ln = (tid & 3) * 8;                  // linear col (A fp32 loads)
    const int sc_sw = slot * 8;                       // permuted col (B gload)
    const int ws0 = sr0 * 64 + slot * 16;             // swizzled LDS write bytes (A)
    const int ws1 = sr1 * 64 + slot * 16;

    const float* Ar0f = Af + (size_t)(m0 + sr0) * K + sc_ln;
    const float* Ar1f = Af + (size_t)(m0 + sr1) * K + sc_ln;
    const __hip_bfloat16* Br0 = Bt + (size_t)(n0 + sr0) * K + sc_sw;
    const __hip_bfloat16* Br1 = Bt + (size_t)(n0 + sr1) * K + sc_sw;

    const int fr = lane & 15;
    const int kb = (lane >> 4) * 16;                  // byte col base
    const int swzg = ((fr >> 1) & 3) << 4;            // read swizzle (bytes)

    // prologue
    float4 a0a = *(const float4*)(Ar0f);
    float4 a0b = *(const float4*)(Ar0f + 4);
    float4 a1a = *(const float4*)(Ar1f);
    float4 a1b = *(const float4*)(Ar1f + 4);
    GLOAD16(Br0, (char*)&Bs[0][0] + tid * 16);
    GLOAD16(Br1, (char*)&Bs[0][0] + 4096 + tid * 16);
    *(short8*)((char*)&As[0][0] + ws0) = pack_bf16x8(a0a, a0b);
    *(short8*)((char*)&As[0][0] + ws1) = pack_bf16x8(a1a, a1b);
    __syncthreads();

    int cur = 0;
    for (int kk = 0; kk < K; kk += 32) {
        const int nxt = cur ^ 1;
        const bool more = (kk + 32 < K);
        if (more) {
            a0a = *(const float4*)(Ar0f + kk + 32);
            a0b = *(const float4*)(Ar0f + kk + 36);
            a1a = *(const float4*)(Ar1f + kk + 32);
            a1b = *(const float4*)(Ar1f + kk + 36);
            GLOAD16(Br0 + kk + 32, (char*)&Bs[nxt][0] + tid * 16);
            GLOAD16(Br1 + kk + 32, (char*)&Bs[nxt][0] + 4096 + tid * 16);
        }
        short8 a[4], b[4];
        #pragma unroll
        for (int m = 0; m < 4; ++m)
            a[m] = *(const short8*)((char*)&As[cur][0] +
                    (wr * 64 + m * 16 + fr) * 64 + (kb ^ swzg));
        #pragma unroll
        for (int n = 0; n < 4; ++n)
            b[n] = *(const short8*)((char*)&Bs[cur][0] +
                    (wc * 64 + n * 16 + fr) * 64 + (kb ^ swzg));
        #pragma unroll
        for (int m = 0; m < 4; ++m)
            #pragma unroll
            for (int n = 0; n < 4; ++n)
                acc[m][n] = __builtin_amdgcn_mfma_f32_16x16x32_bf16(a[m], b[n], acc[m][n], 0, 0, 0);
        if (more) {
            *(short8*)((char*)&As[nxt][0] + ws0) = pack_bf16x8(a0a, a0b);
            *(short8*)((char*)&As[nxt][0] + ws1) = pack_bf16x8(a1a, a1b);
        }
        __syncthreads();
        cur = nxt;
    }

    const int rowb  = m0 + wr * 64 + (lane >> 4) * 4;
    const int colb0 = n0 + wc * 64;

    if (n0 < 1280) {
        const float extra = (n0 < 1024) ? 0.18033688f : 1.0f;   // 0.125*log2(e) | 1
        #pragma unroll
        for (int m = 0; m < 4; ++m)
            #pragma unroll
            for (int r = 0; r < 4; ++r) {
                float ss = 0.f;
                #pragma unroll
                for (int n = 0; n < 4; ++n) { float v = acc[m][n][r]; ss += v * v; }
                ss += __shfl_xor(ss, 1, 64);
                ss += __shfl_xor(ss, 2, 64);
                ss += __shfl_xor(ss, 4, 64);
                ss += __shfl_xor(ss, 8, 64);
                float sc = extra / (sqrtf(ss) + 1e-10f);
                const size_t rbase = (size_t)(rowb + m * 16 + r) * QKVW + colb0 + fr;
                #pragma unroll
                for (int n = 0; n < 4; ++n)
                    qkv[rbase + n * 16] = __float2bfloat16(acc[m][n][r] * sc);
            }
    } else {
        #pragma unroll
        for (int m = 0; m < 4; ++m) {
            const int row = rowb + m * 16;
            const int bb  = row >> 10;
            const int t0  = row & 1023;
            #pragma unroll
            for (int n = 0; n < 4; ++n) {
                const int cv = colb0 + fr + n * 16 - 1280;   // 0..255
                const int gg = cv >> 6, d = cv & 63;
                union { short4v s; __hip_bfloat16 h[4]; } u;
                u.h[0] = __float2bfloat16(acc[m][n][0]);
                u.h[1] = __float2bfloat16(acc[m][n][1]);
                u.h[2] = __float2bfloat16(acc[m][n][2]);
                u.h[3] = __float2bfloat16(acc[m][n][3]);
                *reinterpret_cast<short4v*>(
                    vt + ((size_t)((bb * G_ + gg) * HD_ + d)) * T_ + t0) = u.s;
            }
        }
    }
}

// ---------------------------------------------------------------------------
// Output projection GEMM (verified best config): C = A * Bt^T -> fp32.
// Both operands global_load_lds (slot-permuted source), 2-buffer 2-phase.
// ---------------------------------------------------------------------------
__global__ __launch_bounds__(256) void gemm_tn_f32(
    const __hip_bfloat16* __restrict__ A,
    const __hip_bfloat16* __restrict__ Bt,
    float* __restrict__ C, int M, int N, int K)
{
    __shared__ __hip_bfloat16 As[2][128 * 32];
    __shared__ __hip_bfloat16 Bs[2][128 * 32];

    const int tid  = threadIdx.x;
    const int lane = tid & 63;
    const int wr   = (tid >> 6) >> 1;
    const int wc   = (tid >> 6) & 1;

    const int rpx = (M >> 7) >> 3;
    const int xcd = blockIdx.x & 7;
    const int lin = blockIdx.x >> 3;
    const int by  = xcd * rpx + (lin % rpx);
    const int bx  = lin / rpx;
    const int m0 = by * 128;
    const int n0 = bx * 128;

    f32x4 acc[4][4] = {};

    const int sr0 = tid >> 2;
    const int sr1 = 64 + sr0;
    const int slot  = (tid & 3) ^ ((tid >> 3) & 3);
    const int sc_sw = slot * 8;

    const __hip_bfloat16* Ar0 = A  + (size_t)(m0 + sr0) * K + sc_sw;
    const __hip_bfloat16* Ar1 = A  + (size_t)(m0 + sr1) * K + sc_sw;
    const __hip_bfloat16* Br0 = Bt + (size_t)(n0 + sr0) * K + sc_sw;
    const __hip_bfloat16* Br1 = Bt + (size_t)(n0 + sr1) * K + sc_sw;

    const int fr = lane & 15;
    const int kb = (lane >> 4) * 16;
    const int swzg = ((fr >> 1) & 3) << 4;

    GLOAD16(Ar0, (char*)&As[0][0] + tid * 16);
    GLOAD16(Ar1, (char*)&As[0][0] + 4096 + tid * 16);
    GLOAD16(Br0, (char*)&Bs[0][0] + tid * 16);
    GLOAD16(Br1, (char*)&Bs[0][0] + 4096 + tid * 16);
    __syncthreads();

    int cur = 0;
    for (int kk = 0; kk < K; kk += 32) {
        const int nxt = cur ^ 1;
        if (kk + 32 < K) {
            GLOAD16(Ar0 + kk + 32, (char*)&As[nxt][0] + tid * 16);
            GLOAD16(Ar1 + kk + 32, (char*)&As[nxt][0] + 4096 + tid * 16);
            GLOAD16(Br0 + kk + 32, (char*)&Bs[nxt][0] + tid * 16);
            GLOAD16(Br1 + kk + 32, (char*)&Bs[nxt][0] + 4096 + tid * 16);
        }
        short8 a[4], b[4];
        #pragma unroll
        for (int m = 0; m < 4; ++m)
            a[m] = *(const short8*)((char*)&As[cur][0] +
                    (wr * 64 + m * 16 + fr) * 64 + (kb ^ swzg));
        #pragma unroll
        for (int n = 0; n < 4; ++n)
            b[n] = *(const short8*)((char*)&Bs[cur][0] +
                    (wc * 64 + n * 16 + fr) * 64 + (kb ^ swzg));
        #pragma unroll
        for (int m = 0; m < 4; ++m)
            #pragma unroll
            for (int n = 0; n < 4; ++n)
                acc[m][n] = __builtin_amdgcn_mfma_f32_16x16x32_bf16(a[m], b[n], acc[m][n], 0, 0, 0);
        __syncthreads();
        cur = nxt;
    }

    const int rowb = m0 + wr * 64 + (lane >> 4) * 4;
    const int colb = n0 + wc * 64 + fr;
    #pragma unroll
    for (int m = 0; m < 4; ++m)
        #pragma unroll
        for (int n = 0; n < 4; ++n)
            #pragma unroll
            for (int r = 0; r < 4; ++r)
                C[(size_t)(rowb + m * 16 + r) * N + colb + n * 16] = acc[m][n][r];
}

// ---------------------------------------------------------------------------
// Flash attention, causal, GQA, QBLK=128, XCD-grouped 1D grid. THREE 64-k
// tiles staged per barrier region (K 24KB + V 24KB + P 16KB = 64KB LDS;
// 2 blocks/CU unchanged). Degenerate softmax p=exp2(s) (scale folded into q),
// deferred row-sum, setprio around MFMA.
// ---------------------------------------------------------------------------
__global__ __launch_bounds__(256) void attn_fwd(
    const __hip_bfloat16* __restrict__ qkv,
    const __hip_bfloat16* __restrict__ vt,
    __hip_bfloat16* __restrict__ out)   // [B,T,H*HD]
{
    const int i      = blockIdx.x;
    const int xcd    = i & 7;
    const int j      = i >> 3;
    const int group  = xcd * 4 + (j >> 4);   // 0..31 = b*G+g
    const int member = j & 15;
    const int b    = group >> 2;
    const int g    = group & 3;
    const int h    = g * 4 + (member >> 2);
    const int pair = member & 3;             // 0..3

    const int tid  = threadIdx.x;
    const int lane = tid & 63;
    const int wid  = tid >> 6;

    __shared__ __hip_bfloat16 Ks[3 * 4096];   // three 64x64 swizzled tiles
    __shared__ __hip_bfloat16 Vs[3 * 4096];
    __shared__ __hip_bfloat16 Ps[4 * 2048];   // per wave [32][64] swizzled

    const int fr  = lane & 15;
    const int kf  = (lane >> 4) * 8;
    const int kb  = kf * 2;
    const int swz = (fr & 7) << 4;

    const int srow = tid >> 3;                              // 0..31
    const int scol = ((tid & 7) * 8) ^ ((srow & 7) << 3);   // pre-swizzled col

    const size_t kgbase = (size_t)(b * T_) * QKVW + H_ * HD_ + g * HD_ + scol;
    const size_t vgbase = (size_t)((b * G_ + g) * HD_) * T_ + scol;

    char* PsB = (char*)Ps + wid * 4096;       // 32 rows x 128 B

    auto stage = [&](int kt, int sl) {
        GLOAD16(qkv + kgbase + (size_t)(kt * 64 + srow) * QKVW,
                (char*)Ks + sl * 8192 + tid * 16);
        GLOAD16(qkv + kgbase + (size_t)(kt * 64 + 32 + srow) * QKVW,
                (char*)Ks + sl * 8192 + 4096 + tid * 16);
        GLOAD16(vt + vgbase + (size_t)srow * T_ + kt * 64,
                (char*)Vs + sl * 8192 + tid * 16);
        GLOAD16(vt + vgbase + (size_t)(32 + srow) * T_ + kt * 64,
                (char*)Vs + sl * 8192 + 4096 + tid * 16);
    };

    for (int half = 0; half < 2; ++half) {
        const int qt  = half ? (7 - pair) : pair;   // 128-row q-tile
        const int q0  = qt * 128;
        const int nkt = 2 * qt + 2;                 // 64-col k-tiles (even)

        short8 qf[2][2];
        #pragma unroll
        for (int m = 0; m < 2; ++m) {
            const size_t qbase =
                ((size_t)(b * T_ + q0 + wid * 32 + m * 16 + fr)) * QKVW + h * HD_;
            qf[m][0] = *(const short8*)(qkv + qbase + kf);
            qf[m][1] = *(const short8*)(qkv + qbase + 32 + kf);
        }
        const int rb0 = q0 + wid * 32 + (lane >> 4) * 4;

        float lsum[2][4] = {};
        f32x4 o[2][4] = {};

        auto compute = [&](int ck, int sl) {
            const bool msk = (ck >= nkt - 2);
            char* KsB = (char*)Ks + sl * 8192;
            char* VsB = (char*)Vs + sl * 8192;

            short8 bk0[4], bk1[4];
            #pragma unroll
            for (int nf = 0; nf < 4; ++nf) {
                const int row = fr + 16 * nf;
                bk0[nf] = *(const short8*)(KsB + row * 128 + (kb ^ swz));
                bk1[nf] = *(const short8*)(KsB + row * 128 + ((64 + kb) ^ swz));
            }

            #pragma unroll
            for (int m = 0; m < 2; ++m) {
                f32x4 s[4] = {};
                __builtin_amdgcn_s_setprio(1);
                #pragma unroll
                for (int nf = 0; nf < 4; ++nf) {
                    s[nf] = __builtin_amdgcn_mfma_f32_16x16x32_bf16(qf[m][0], bk0[nf], s[nf], 0, 0, 0);
                    s[nf] = __builtin_amdgcn_mfma_f32_16x16x32_bf16(qf[m][1], bk1[nf], s[nf], 0, 0, 0);
                }
                __builtin_amdgcn_s_setprio(0);

                if (msk) {
                    #pragma unroll
                    for (int nf = 0; nf < 4; ++nf) {
                        int col = ck * 64 + fr + 16 * nf;
                        #pragma unroll
                        for (int r = 0; r < 4; ++r) {
                            float p = (col <= rb0 + m * 16 + r) ? exp2_fast(s[nf][r]) : 0.f;
                            lsum[m][r] += p;
                            int q = m * 16 + (lane >> 4) * 4 + r;
                            *(__hip_bfloat16*)(PsB + q * 128 +
                                ((2 * (fr + 16 * nf)) ^ ((q & 7) << 4))) = __float2bfloat16(p);
                        }
                    }
                } else {
                    #pragma unroll
                    for (int nf = 0; nf < 4; ++nf)
                        #pragma unroll
                        for (int r = 0; r < 4; ++r) {
                            float p = exp2_fast(s[nf][r]);
                            lsum[m][r] += p;
                            int q = m * 16 + (lane >> 4) * 4 + r;
                            *(__hip_bfloat16*)(PsB + q * 128 +
                                ((2 * (fr + 16 * nf)) ^ ((q & 7) << 4))) = __float2bfloat16(p);
                        }
                }
            }

            short8 bv0[4], bv1[4];
            #pragma unroll
            for (int nf = 0; nf < 4; ++nf) {
                const int row = fr + 16 * nf;
                bv0[nf] = *(const short8*)(VsB + row * 128 + (kb ^ swz));
                bv1[nf] = *(const short8*)(VsB + row * 128 + ((64 + kb) ^ swz));
            }
            __builtin_amdgcn_s_setprio(1);
            #pragma unroll
            for (int m = 0; m < 2; ++m) {
                short8 pa0 = *(const short8*)(PsB + (m * 16 + fr) * 128 + (kb ^ swz));
                short8 pa1 = *(const short8*)(PsB + (m * 16 + fr) * 128 + ((64 + kb) ^ swz));
                #pragma unroll
                for (int nf = 0; nf < 4; ++nf) {
                    o[m][nf] = __builtin_amdgcn_mfma_f32_16x16x32_bf16(pa0, bv0[nf], o[m][nf], 0, 0, 0);
                    o[m][nf] = __builtin_amdgcn_mfma_f32_16x16x32_bf16(pa1, bv1[nf], o[m][nf], 0, 0, 0);
                }
            }
            __builtin_amdgcn_s_setprio(0);
        };

        int kt = 0;
        while (kt < nkt) {
            const int rem = nkt - kt;
            const int cnt = (rem >= 3) ? 3 : rem;   // 1, 2, or 3
            if (cnt == 3)      { stage(kt, 0); stage(kt + 1, 1); stage(kt + 2, 2); }
            else if (cnt == 2) { stage(kt, 0); stage(kt + 1, 1); }
            else               { stage(kt, 0); }
            __syncthreads();
            if (cnt == 3)      { compute(kt, 0); compute(kt + 1, 1); compute(kt + 2, 2); }
            else if (cnt == 2) { compute(kt, 0); compute(kt + 1, 1); }
            else               { compute(kt, 0); }
            __syncthreads();
            kt += cnt;
        }

        #pragma unroll
        for (int m = 0; m < 2; ++m) {
            float linv[4];
            #pragma unroll
            for (int r = 0; r < 4; ++r) {
                float v = lsum[m][r];
                v += __shfl_xor(v, 1, 64);
                v += __shfl_xor(v, 2, 64);
                v += __shfl_xor(v, 4, 64);
                v += __shfl_xor(v, 8, 64);
                linv[r] = 1.0f / v;
            }
            #pragma unroll
            for (int nf = 0; nf < 4; ++nf) {
                int col = fr + 16 * nf;
                #pragma unroll
                for (int r = 0; r < 4; ++r) {
                    float v = o[m][nf][r] * linv[r];
                    out[((size_t)(b * T_ + rb0 + m * 16 + r)) * (H_ * HD_) + h * HD_ + col] =
                        __float2bfloat16(v);
                }
            }
        }
    }
}

extern "C" void kernel_launch(void* const* d_in, const int* in_sizes, int n_in,
                              void* d_out, int out_size, void* d_ws, size_t ws_size,
                              hipStream_t stream) {
    const float* x_f     = (const float*)d_in[0];   // [8192,1024]
    const float* w_qkv_f = (const float*)d_in[1];   // [1024,1536]
    const float* w_o_f   = (const float*)d_in[2];   // [1024,1024]
    float* out = (float*)d_out;

    const int NX  = B_ * T_ * D_;
    const int NWQ = D_ * QKVW;
    const int NWO = D_ * D_;

    __hip_bfloat16* attn_out = (__hip_bfloat16*)d_ws;              // [8192][1024]
    __hip_bfloat16* wqkvT = attn_out + NX;                         // [1536][1024]
    __hip_bfloat16* woT   = wqkvT + NWQ;                           // [1024][1024]
    __hip_bfloat16* qkv   = woT + NWO;                             // [8192][1536]
    __hip_bfloat16* vt    = qkv + (size_t)(B_ * T_) * QKVW;        // [B*G*64][1024]

    dim3 blk(256);

    cvt_transpose2<<<dim3(QKVW / 32, D_ / 32, 2), blk, 0, stream>>>(
        w_qkv_f, w_o_f, wqkvT, woT);

    // fused QKV GEMM: 128x128 tiles -> grid 768 (%8==0)
    gemm_qkv<<<dim3((QKVW / 128) * ((B_ * T_) / 128)), blk, 0, stream>>>(
        x_f, wqkvT, qkv, vt);

    // attn: 1D grid, XCD-grouped (512 blocks)
    attn_fwd<<<dim3(4 * H_ * B_), blk, 0, stream>>>(qkv, vt, attn_out);

    // out = attn_out @ w_o: grid 512 (%8==0)
    gemm_tn_f32<<<dim3((D_ / 128) * ((B_ * T_) / 128)), blk, 0, stream>>>(
        attn_out, woT, out, B_ * T_, D_, D_);
}

// Round 21
// 109.866 us; speedup vs baseline: 1.1285x; 1.1285x over previous
//
#include <hip/hip_runtime.h>
#include <hip/hip_bf16.h>

typedef __attribute__((ext_vector_type(8))) short short8;
typedef __attribute__((ext_vector_type(4))) short short4v;
typedef __attribute__((ext_vector_type(4))) float f32x4;

#define B_ 8
#define T_ 1024
#define D_ 1024
#define H_ 16
#define G_ 4
#define HD_ 64
#define QKVW 1536   // 1024 q | 256 k | 256 v

#define GLOAD16(gp, lp) __builtin_amdgcn_global_load_lds( \
    (const __attribute__((address_space(1))) void*)(gp),  \
    (__attribute__((address_space(3))) void*)(lp), 16, 0, 0)

__device__ __forceinline__ float exp2_fast(float x) {
    return __builtin_amdgcn_exp2f(x);
}

__device__ __forceinline__ short8 pack_bf16x8(float4 a, float4 b) {
    union { short8 s; __hip_bfloat16 h[8]; } u;
    u.h[0] = __float2bfloat16(a.x); u.h[1] = __float2bfloat16(a.y);
    u.h[2] = __float2bfloat16(a.z); u.h[3] = __float2bfloat16(a.w);
    u.h[4] = __float2bfloat16(b.x); u.h[5] = __float2bfloat16(b.y);
    u.h[6] = __float2bfloat16(b.z); u.h[7] = __float2bfloat16(b.w);
    return u.s;
}

// ---------------------------------------------------------------------------
// Both weights: fp32 [K][N] -> bf16 transposed [N][K], one launch (z selects).
// ---------------------------------------------------------------------------
__global__ __launch_bounds__(256) void cvt_transpose2(
    const float* __restrict__ w_qkv, const float* __restrict__ w_o,
    __hip_bfloat16* __restrict__ wqkvT, __hip_bfloat16* __restrict__ woT)
{
    const int z = blockIdx.z;
    const int N = z ? D_ : QKVW;
    const int n0 = blockIdx.x * 32;
    if (n0 >= N) return;
    const float* in = z ? w_o : w_qkv;
    __hip_bfloat16* outT = z ? woT : wqkvT;

    __shared__ float tile[32][33];
    const int k0 = blockIdx.y * 32;
    const int r = threadIdx.x >> 5, c = threadIdx.x & 31;
    #pragma unroll
    for (int i = 0; i < 4; ++i)
        tile[r + i * 8][c] = in[(size_t)(k0 + r + i * 8) * N + n0 + c];
    __syncthreads();
    #pragma unroll
    for (int i = 0; i < 4; ++i)
        outT[(size_t)(n0 + r + i * 8) * D_ + k0 + c] = __float2bfloat16(tile[c][r + i * 8]);
}

// ---------------------------------------------------------------------------
// Fused QKV GEMM (verified best config): fp32 A (cvt fused, reg-staged w/
// swizzled ds_write), B via global_load_lds w/ slot-permuted source.
// 2-buffer 2-phase, 32 KB LDS. Epilogue: q/k L2-norm (+scale-fold on q);
// v written transposed to vt.
// ---------------------------------------------------------------------------
__global__ __launch_bounds__(256) void gemm_qkv(
    const float* __restrict__ Af,
    const __hip_bfloat16* __restrict__ Bt,
    __hip_bfloat16* __restrict__ qkv,
    __hip_bfloat16* __restrict__ vt)
{
    const int M = B_ * T_, K = D_;
    __shared__ __hip_bfloat16 As[2][128 * 32];
    __shared__ __hip_bfloat16 Bs[2][128 * 32];

    const int tid  = threadIdx.x;
    const int lane = tid & 63;
    const int wr   = (tid >> 6) >> 1;
    const int wc   = (tid >> 6) & 1;

    const int rpx = (M >> 7) >> 3;          // 8
    const int xcd = blockIdx.x & 7;
    const int lin = blockIdx.x >> 3;
    const int by  = xcd * rpx + (lin % rpx);
    const int bx  = lin / rpx;
    const int m0 = by * 128;
    const int n0 = bx * 128;

    f32x4 acc[4][4] = {};

    const int sr0 = tid >> 2;               // rows 0..63
    const int sr1 = 64 + sr0;               // rows 64..127
    const int slot  = (tid & 3) ^ ((tid >> 3) & 3);   // swizzled 16B slot
    const int sc_ln = (tid & 3) * 8;                  // linear col (A fp32 loads)
    const int sc_sw = slot * 8;                       // permuted col (B gload)
    const int ws0 = sr0 * 64 + slot * 16;             // swizzled LDS write bytes (A)
    const int ws1 = sr1 * 64 + slot * 16;

    const float* Ar0f = Af + (size_t)(m0 + sr0) * K + sc_ln;
    const float* Ar1f = Af + (size_t)(m0 + sr1) * K + sc_ln;
    const __hip_bfloat16* Br0 = Bt + (size_t)(n0 + sr0) * K + sc_sw;
    const __hip_bfloat16* Br1 = Bt + (size_t)(n0 + sr1) * K + sc_sw;

    const int fr = lane & 15;
    const int kb = (lane >> 4) * 16;                  // byte col base
    const int swzg = ((fr >> 1) & 3) << 4;            // read swizzle (bytes)

    // prologue
    float4 a0a = *(const float4*)(Ar0f);
    float4 a0b = *(const float4*)(Ar0f + 4);
    float4 a1a = *(const float4*)(Ar1f);
    float4 a1b = *(const float4*)(Ar1f + 4);
    GLOAD16(Br0, (char*)&Bs[0][0] + tid * 16);
    GLOAD16(Br1, (char*)&Bs[0][0] + 4096 + tid * 16);
    *(short8*)((char*)&As[0][0] + ws0) = pack_bf16x8(a0a, a0b);
    *(short8*)((char*)&As[0][0] + ws1) = pack_bf16x8(a1a, a1b);
    __syncthreads();

    int cur = 0;
    for (int kk = 0; kk < K; kk += 32) {
        const int nxt = cur ^ 1;
        const bool more = (kk + 32 < K);
        if (more) {
            a0a = *(const float4*)(Ar0f + kk + 32);
            a0b = *(const float4*)(Ar0f + kk + 36);
            a1a = *(const float4*)(Ar1f + kk + 32);
            a1b = *(const float4*)(Ar1f + kk + 36);
            GLOAD16(Br0 + kk + 32, (char*)&Bs[nxt][0] + tid * 16);
            GLOAD16(Br1 + kk + 32, (char*)&Bs[nxt][0] + 4096 + tid * 16);
        }
        short8 a[4], b[4];
        #pragma unroll
        for (int m = 0; m < 4; ++m)
            a[m] = *(const short8*)((char*)&As[cur][0] +
                    (wr * 64 + m * 16 + fr) * 64 + (kb ^ swzg));
        #pragma unroll
        for (int n = 0; n < 4; ++n)
            b[n] = *(const short8*)((char*)&Bs[cur][0] +
                    (wc * 64 + n * 16 + fr) * 64 + (kb ^ swzg));
        #pragma unroll
        for (int m = 0; m < 4; ++m)
            #pragma unroll
            for (int n = 0; n < 4; ++n)
                acc[m][n] = __builtin_amdgcn_mfma_f32_16x16x32_bf16(a[m], b[n], acc[m][n], 0, 0, 0);
        if (more) {
            *(short8*)((char*)&As[nxt][0] + ws0) = pack_bf16x8(a0a, a0b);
            *(short8*)((char*)&As[nxt][0] + ws1) = pack_bf16x8(a1a, a1b);
        }
        __syncthreads();
        cur = nxt;
    }

    const int rowb  = m0 + wr * 64 + (lane >> 4) * 4;
    const int colb0 = n0 + wc * 64;

    if (n0 < 1280) {
        const float extra = (n0 < 1024) ? 0.18033688f : 1.0f;   // 0.125*log2(e) | 1
        #pragma unroll
        for (int m = 0; m < 4; ++m)
            #pragma unroll
            for (int r = 0; r < 4; ++r) {
                float ss = 0.f;
                #pragma unroll
                for (int n = 0; n < 4; ++n) { float v = acc[m][n][r]; ss += v * v; }
                ss += __shfl_xor(ss, 1, 64);
                ss += __shfl_xor(ss, 2, 64);
                ss += __shfl_xor(ss, 4, 64);
                ss += __shfl_xor(ss, 8, 64);
                float sc = extra / (sqrtf(ss) + 1e-10f);
                const size_t rbase = (size_t)(rowb + m * 16 + r) * QKVW + colb0 + fr;
                #pragma unroll
                for (int n = 0; n < 4; ++n)
                    qkv[rbase + n * 16] = __float2bfloat16(acc[m][n][r] * sc);
            }
    } else {
        #pragma unroll
        for (int m = 0; m < 4; ++m) {
            const int row = rowb + m * 16;
            const int bb  = row >> 10;
            const int t0  = row & 1023;
            #pragma unroll
            for (int n = 0; n < 4; ++n) {
                const int cv = colb0 + fr + n * 16 - 1280;   // 0..255
                const int gg = cv >> 6, d = cv & 63;
                union { short4v s; __hip_bfloat16 h[4]; } u;
                u.h[0] = __float2bfloat16(acc[m][n][0]);
                u.h[1] = __float2bfloat16(acc[m][n][1]);
                u.h[2] = __float2bfloat16(acc[m][n][2]);
                u.h[3] = __float2bfloat16(acc[m][n][3]);
                *reinterpret_cast<short4v*>(
                    vt + ((size_t)((bb * G_ + gg) * HD_ + d)) * T_ + t0) = u.s;
            }
        }
    }
}

// ---------------------------------------------------------------------------
// Output projection GEMM (verified best config): C = A * Bt^T -> fp32.
// Both operands global_load_lds (slot-permuted source), 2-buffer 2-phase.
// ---------------------------------------------------------------------------
__global__ __launch_bounds__(256) void gemm_tn_f32(
    const __hip_bfloat16* __restrict__ A,
    const __hip_bfloat16* __restrict__ Bt,
    float* __restrict__ C, int M, int N, int K)
{
    __shared__ __hip_bfloat16 As[2][128 * 32];
    __shared__ __hip_bfloat16 Bs[2][128 * 32];

    const int tid  = threadIdx.x;
    const int lane = tid & 63;
    const int wr   = (tid >> 6) >> 1;
    const int wc   = (tid >> 6) & 1;

    const int rpx = (M >> 7) >> 3;
    const int xcd = blockIdx.x & 7;
    const int lin = blockIdx.x >> 3;
    const int by  = xcd * rpx + (lin % rpx);
    const int bx  = lin / rpx;
    const int m0 = by * 128;
    const int n0 = bx * 128;

    f32x4 acc[4][4] = {};

    const int sr0 = tid >> 2;
    const int sr1 = 64 + sr0;
    const int slot  = (tid & 3) ^ ((tid >> 3) & 3);
    const int sc_sw = slot * 8;

    const __hip_bfloat16* Ar0 = A  + (size_t)(m0 + sr0) * K + sc_sw;
    const __hip_bfloat16* Ar1 = A  + (size_t)(m0 + sr1) * K + sc_sw;
    const __hip_bfloat16* Br0 = Bt + (size_t)(n0 + sr0) * K + sc_sw;
    const __hip_bfloat16* Br1 = Bt + (size_t)(n0 + sr1) * K + sc_sw;

    const int fr = lane & 15;
    const int kb = (lane >> 4) * 16;
    const int swzg = ((fr >> 1) & 3) << 4;

    GLOAD16(Ar0, (char*)&As[0][0] + tid * 16);
    GLOAD16(Ar1, (char*)&As[0][0] + 4096 + tid * 16);
    GLOAD16(Br0, (char*)&Bs[0][0] + tid * 16);
    GLOAD16(Br1, (char*)&Bs[0][0] + 4096 + tid * 16);
    __syncthreads();

    int cur = 0;
    for (int kk = 0; kk < K; kk += 32) {
        const int nxt = cur ^ 1;
        if (kk + 32 < K) {
            GLOAD16(Ar0 + kk + 32, (char*)&As[nxt][0] + tid * 16);
            GLOAD16(Ar1 + kk + 32, (char*)&As[nxt][0] + 4096 + tid * 16);
            GLOAD16(Br0 + kk + 32, (char*)&Bs[nxt][0] + tid * 16);
            GLOAD16(Br1 + kk + 32, (char*)&Bs[nxt][0] + 4096 + tid * 16);
        }
        short8 a[4], b[4];
        #pragma unroll
        for (int m = 0; m < 4; ++m)
            a[m] = *(const short8*)((char*)&As[cur][0] +
                    (wr * 64 + m * 16 + fr) * 64 + (kb ^ swzg));
        #pragma unroll
        for (int n = 0; n < 4; ++n)
            b[n] = *(const short8*)((char*)&Bs[cur][0] +
                    (wc * 64 + n * 16 + fr) * 64 + (kb ^ swzg));
        #pragma unroll
        for (int m = 0; m < 4; ++m)
            #pragma unroll
            for (int n = 0; n < 4; ++n)
                acc[m][n] = __builtin_amdgcn_mfma_f32_16x16x32_bf16(a[m], b[n], acc[m][n], 0, 0, 0);
        __syncthreads();
        cur = nxt;
    }

    const int rowb = m0 + wr * 64 + (lane >> 4) * 4;
    const int colb = n0 + wc * 64 + fr;
    #pragma unroll
    for (int m = 0; m < 4; ++m)
        #pragma unroll
        for (int n = 0; n < 4; ++n)
            #pragma unroll
            for (int r = 0; r < 4; ++r)
                C[(size_t)(rowb + m * 16 + r) * N + colb + n * 16] = acc[m][n][r];
}

// ---------------------------------------------------------------------------
// Flash attention, causal, GQA, QBLK=128 (verified best config): 1D grid,
// XCD-grouped; two 64-k tiles per barrier region (40 KB LDS, 2 blocks/CU);
// degenerate softmax p=exp2(s) (scale folded into q), deferred row-sum,
// setprio around MFMA.
// ---------------------------------------------------------------------------
__global__ __launch_bounds__(256) void attn_fwd(
    const __hip_bfloat16* __restrict__ qkv,
    const __hip_bfloat16* __restrict__ vt,
    __hip_bfloat16* __restrict__ out)   // [B,T,H*HD]
{
    const int i      = blockIdx.x;
    const int xcd    = i & 7;
    const int j      = i >> 3;
    const int group  = xcd * 4 + (j >> 4);   // 0..31 = b*G+g
    const int member = j & 15;
    const int b    = group >> 2;
    const int g    = group & 3;
    const int h    = g * 4 + (member >> 2);
    const int pair = member & 3;             // 0..3

    const int tid  = threadIdx.x;
    const int lane = tid & 63;
    const int wid  = tid >> 6;

    __shared__ __hip_bfloat16 Ks[2 * 4096];   // two 64x64 swizzled tiles
    __shared__ __hip_bfloat16 Vs[2 * 4096];
    __shared__ __hip_bfloat16 Ps[4 * 2048];   // per wave [32][64] swizzled

    const int fr  = lane & 15;
    const int kf  = (lane >> 4) * 8;
    const int kb  = kf * 2;
    const int swz = (fr & 7) << 4;

    const int srow = tid >> 3;                              // 0..31
    const int scol = ((tid & 7) * 8) ^ ((srow & 7) << 3);   // pre-swizzled col

    const size_t kgbase = (size_t)(b * T_) * QKVW + H_ * HD_ + g * HD_ + scol;
    const size_t vgbase = (size_t)((b * G_ + g) * HD_) * T_ + scol;

    char* PsB = (char*)Ps + wid * 4096;       // 32 rows x 128 B

    auto stage = [&](int kt, int sl) {
        GLOAD16(qkv + kgbase + (size_t)(kt * 64 + srow) * QKVW,
                (char*)Ks + sl * 8192 + tid * 16);
        GLOAD16(qkv + kgbase + (size_t)(kt * 64 + 32 + srow) * QKVW,
                (char*)Ks + sl * 8192 + 4096 + tid * 16);
        GLOAD16(vt + vgbase + (size_t)srow * T_ + kt * 64,
                (char*)Vs + sl * 8192 + tid * 16);
        GLOAD16(vt + vgbase + (size_t)(32 + srow) * T_ + kt * 64,
                (char*)Vs + sl * 8192 + 4096 + tid * 16);
    };

    for (int half = 0; half < 2; ++half) {
        const int qt  = half ? (7 - pair) : pair;   // 128-row q-tile
        const int q0  = qt * 128;
        const int nkt = 2 * qt + 2;                 // 64-col k-tiles

        short8 qf[2][2];
        #pragma unroll
        for (int m = 0; m < 2; ++m) {
            const size_t qbase =
                ((size_t)(b * T_ + q0 + wid * 32 + m * 16 + fr)) * QKVW + h * HD_;
            qf[m][0] = *(const short8*)(qkv + qbase + kf);
            qf[m][1] = *(const short8*)(qkv + qbase + 32 + kf);
        }
        const int rb0 = q0 + wid * 32 + (lane >> 4) * 4;

        float lsum[2][4] = {};
        f32x4 o[2][4] = {};

        for (int kt = 0; kt < nkt; kt += 2) {
            stage(kt, 0);
            stage(kt + 1, 1);
            __syncthreads();

            #pragma unroll
            for (int sl = 0; sl < 2; ++sl) {
                const int  ck  = kt + sl;
                const bool msk = (ck >= nkt - 2);
                char* KsB = (char*)Ks + sl * 8192;
                char* VsB = (char*)Vs + sl * 8192;

                short8 bk0[4], bk1[4];
                #pragma unroll
                for (int nf = 0; nf < 4; ++nf) {
                    const int row = fr + 16 * nf;
                    bk0[nf] = *(const short8*)(KsB + row * 128 + (kb ^ swz));
                    bk1[nf] = *(const short8*)(KsB + row * 128 + ((64 + kb) ^ swz));
                }

                #pragma unroll
                for (int m = 0; m < 2; ++m) {
                    f32x4 s[4] = {};
                    __builtin_amdgcn_s_setprio(1);
                    #pragma unroll
                    for (int nf = 0; nf < 4; ++nf) {
                        s[nf] = __builtin_amdgcn_mfma_f32_16x16x32_bf16(qf[m][0], bk0[nf], s[nf], 0, 0, 0);
                        s[nf] = __builtin_amdgcn_mfma_f32_16x16x32_bf16(qf[m][1], bk1[nf], s[nf], 0, 0, 0);
                    }
                    __builtin_amdgcn_s_setprio(0);

                    if (msk) {
                        #pragma unroll
                        for (int nf = 0; nf < 4; ++nf) {
                            int col = ck * 64 + fr + 16 * nf;
                            #pragma unroll
                            for (int r = 0; r < 4; ++r) {
                                float p = (col <= rb0 + m * 16 + r) ? exp2_fast(s[nf][r]) : 0.f;
                                lsum[m][r] += p;
                                int q = m * 16 + (lane >> 4) * 4 + r;
                                *(__hip_bfloat16*)(PsB + q * 128 +
                                    ((2 * (fr + 16 * nf)) ^ ((q & 7) << 4))) = __float2bfloat16(p);
                            }
                        }
                    } else {
                        #pragma unroll
                        for (int nf = 0; nf < 4; ++nf)
                            #pragma unroll
                            for (int r = 0; r < 4; ++r) {
                                float p = exp2_fast(s[nf][r]);
                                lsum[m][r] += p;
                                int q = m * 16 + (lane >> 4) * 4 + r;
                                *(__hip_bfloat16*)(PsB + q * 128 +
                                    ((2 * (fr + 16 * nf)) ^ ((q & 7) << 4))) = __float2bfloat16(p);
                            }
                    }
                }

                short8 bv0[4], bv1[4];
                #pragma unroll
                for (int nf = 0; nf < 4; ++nf) {
                    const int row = fr + 16 * nf;
                    bv0[nf] = *(const short8*)(VsB + row * 128 + (kb ^ swz));
                    bv1[nf] = *(const short8*)(VsB + row * 128 + ((64 + kb) ^ swz));
                }
                __builtin_amdgcn_s_setprio(1);
                #pragma unroll
                for (int m = 0; m < 2; ++m) {
                    short8 pa0 = *(const short8*)(PsB + (m * 16 + fr) * 128 + (kb ^ swz));
                    short8 pa1 = *(const short8*)(PsB + (m * 16 + fr) * 128 + ((64 + kb) ^ swz));
                    #pragma unroll
                    for (int nf = 0; nf < 4; ++nf) {
                        o[m][nf] = __builtin_amdgcn_mfma_f32_16x16x32_bf16(pa0, bv0[nf], o[m][nf], 0, 0, 0);
                        o[m][nf] = __builtin_amdgcn_mfma_f32_16x16x32_bf16(pa1, bv1[nf], o[m][nf], 0, 0, 0);
                    }
                }
                __builtin_amdgcn_s_setprio(0);
            }
            __syncthreads();
        }

        #pragma unroll
        for (int m = 0; m < 2; ++m) {
            float linv[4];
            #pragma unroll
            for (int r = 0; r < 4; ++r) {
                float v = lsum[m][r];
                v += __shfl_xor(v, 1, 64);
                v += __shfl_xor(v, 2, 64);
                v += __shfl_xor(v, 4, 64);
                v += __shfl_xor(v, 8, 64);
                linv[r] = 1.0f / v;
            }
            #pragma unroll
            for (int nf = 0; nf < 4; ++nf) {
                int col = fr + 16 * nf;
                #pragma unroll
                for (int r = 0; r < 4; ++r) {
                    float v = o[m][nf][r] * linv[r];
                    out[((size_t)(b * T_ + rb0 + m * 16 + r)) * (H_ * HD_) + h * HD_ + col] =
                        __float2bfloat16(v);
                }
            }
        }
    }
}

extern "C" void kernel_launch(void* const* d_in, const int* in_sizes, int n_in,
                              void* d_out, int out_size, void* d_ws, size_t ws_size,
                              hipStream_t stream) {
    const float* x_f     = (const float*)d_in[0];   // [8192,1024]
    const float* w_qkv_f = (const float*)d_in[1];   // [1024,1536]
    const float* w_o_f   = (const float*)d_in[2];   // [1024,1024]
    float* out = (float*)d_out;

    const int NX  = B_ * T_ * D_;
    const int NWQ = D_ * QKVW;
    const int NWO = D_ * D_;

    __hip_bfloat16* attn_out = (__hip_bfloat16*)d_ws;              // [8192][1024]
    __hip_bfloat16* wqkvT = attn_out + NX;                         // [1536][1024]
    __hip_bfloat16* woT   = wqkvT + NWQ;                           // [1024][1024]
    __hip_bfloat16* qkv   = woT + NWO;                             // [8192][1536]
    __hip_bfloat16* vt    = qkv + (size_t)(B_ * T_) * QKVW;        // [B*G*64][1024]

    dim3 blk(256);

    cvt_transpose2<<<dim3(QKVW / 32, D_ / 32, 2), blk, 0, stream>>>(
        w_qkv_f, w_o_f, wqkvT, woT);

    // fused QKV GEMM: 128x128 tiles -> grid 768 (%8==0)
    gemm_qkv<<<dim3((QKVW / 128) * ((B_ * T_) / 128)), blk, 0, stream>>>(
        x_f, wqkvT, qkv, vt);

    // attn: 1D grid, XCD-grouped (512 blocks)
    attn_fwd<<<dim3(4 * H_ * B_), blk, 0, stream>>>(qkv, vt, attn_out);

    // out = attn_out @ w_o: grid 512 (%8==0)
    gemm_tn_f32<<<dim3((D_ / 128) * ((B_ * T_) / 128)), blk, 0, stream>>>(
        attn_out, woT, out, B_ * T_, D_, D_);
}